// Round 2
// baseline (740.170 us; speedup 1.0000x reference)
//
#include <hip/hip_runtime.h>

// Problem constants (from reference): N=1e6 rows, D=128, B=8192 segments, H=512.
#define DIM 128
#define HID 512
#define NSEG 8192
#define MLP_ROWS 16   // rows of the [B,256] input per mlp block

// ---------------------------------------------------------------------------
// Kernel 1: segment boundaries from sorted batch ids.
// seg_start[s] = first row index i with batch[i] >= s ; seg_start[B] = N.
// Every entry of seg_start[0..B] is written exactly once (head / change-point /
// tail coverage), so the 0xAA-poisoned workspace needs no memset.
// ---------------------------------------------------------------------------
__global__ __launch_bounds__(256) void boundaries_kernel(
    const int* __restrict__ batch, int* __restrict__ seg_start, int N, int B)
{
    int i = blockIdx.x * 256 + threadIdx.x;
    if (i >= N) return;
    int b = batch[i];
    if (i == 0) {
        for (int s = 0; s <= b; ++s) seg_start[s] = 0;
    } else {
        int p = batch[i - 1];
        for (int s = p + 1; s <= b; ++s) seg_start[s] = i;
    }
    if (i == N - 1) {
        for (int s = b + 1; s <= B; ++s) seg_start[s] = N;
    }
}

// ---------------------------------------------------------------------------
// Kernel 2: per-segment mean. One block per segment; rows are contiguous.
// 8 row-phases x 32 col-threads, float4 per thread (512B coalesced per row).
// 2-way unrolled (rows r and r+8) -> 2 loads in flight per lane.
// ---------------------------------------------------------------------------
__global__ __launch_bounds__(256) void seg_mean_kernel(
    const float* __restrict__ x, const int* __restrict__ seg_start,
    float* __restrict__ xmean)
{
    __shared__ float4 part[8][32];
    const int s   = blockIdx.x;
    const int lo  = seg_start[s];
    const int hi  = seg_start[s + 1];
    const int tid = threadIdx.x;
    const int colg  = tid & 31;   // float4 column group: cols 4*colg..4*colg+3
    const int phase = tid >> 5;   // 0..7

    float4 a0 = make_float4(0.f, 0.f, 0.f, 0.f);
    float4 a1 = make_float4(0.f, 0.f, 0.f, 0.f);
    const float* base = x + (size_t)colg * 4;
    int r = lo + phase;
    for (; r + 8 < hi; r += 16) {
        const float4 v0 = *reinterpret_cast<const float4*>(base + (size_t)r * DIM);
        const float4 v1 = *reinterpret_cast<const float4*>(base + (size_t)(r + 8) * DIM);
        a0.x += v0.x; a0.y += v0.y; a0.z += v0.z; a0.w += v0.w;
        a1.x += v1.x; a1.y += v1.y; a1.z += v1.z; a1.w += v1.w;
    }
    if (r < hi) {
        const float4 v0 = *reinterpret_cast<const float4*>(base + (size_t)r * DIM);
        a0.x += v0.x; a0.y += v0.y; a0.z += v0.z; a0.w += v0.w;
    }
    a0.x += a1.x; a0.y += a1.y; a0.z += a1.z; a0.w += a1.w;
    part[phase][colg] = a0;
    __syncthreads();

    if (tid < 32) {
        float4 t = part[0][tid];
        #pragma unroll
        for (int p = 1; p < 8; ++p) {
            float4 u = part[p][tid];
            t.x += u.x; t.y += u.y; t.z += u.z; t.w += u.w;
        }
        const float inv = (hi > lo) ? 1.0f / (float)(hi - lo) : 0.0f;
        t.x *= inv; t.y *= inv; t.z *= inv; t.w *= inv;
        *reinterpret_cast<float4*>(xmean + (size_t)s * DIM + tid * 4) = t;
    }
}

// ---------------------------------------------------------------------------
// Kernel 3: fused MLP.  out = relu([xmean, xvc] @ W1 + b1) @ W2 + b2
// Block = 256 threads, 16 rows. X tile (16x256) + H tile (16x512) in LDS
// (48 KiB -> 3 blocks/CU). Stage B: thread = 4 cols x 8 rows (k-unroll 4).
// Stage C: thread = 4 cols x 2 rows. Xs/Hs reads are wave-uniform broadcasts.
// ---------------------------------------------------------------------------
__global__ __launch_bounds__(256) void mlp_kernel(
    const float* __restrict__ xmean, const float* __restrict__ xvc,
    const float* __restrict__ W1, const float* __restrict__ b1,
    const float* __restrict__ W2, const float* __restrict__ b2,
    float* __restrict__ out)
{
    __shared__ float Xs[MLP_ROWS][2 * DIM];   // 16 KiB
    __shared__ float Hs[MLP_ROWS][HID];       // 32 KiB
    const int tid  = threadIdx.x;
    const int row0 = blockIdx.x * MLP_ROWS;

    // ---- load X tile (vectorized): cols 0..127 = xmean, 128..255 = xvc
    #pragma unroll
    for (int i = 0; i < 4; ++i) {
        const int flat = tid + 256 * i;   // 0..1023 float4 slots
        const int r    = flat >> 6;       // 0..15
        const int cg   = flat & 63;       // float4 col group 0..63
        const float4 v = (cg < 32)
            ? *reinterpret_cast<const float4*>(xmean + (size_t)(row0 + r) * DIM + cg * 4)
            : *reinterpret_cast<const float4*>(xvc   + (size_t)(row0 + r) * DIM + (cg - 32) * 4);
        *reinterpret_cast<float4*>(&Xs[r][cg * 4]) = v;
    }
    __syncthreads();

    // ---- stage B: H = relu(X @ W1 + b1), W1 is [256][512] row-major
    {
        const int cg = tid & 127;
        const int c0 = cg << 2;              // 4 consecutive H columns
        const int rb = (tid >> 7) << 3;      // row base: 0 or 8
        float acc[8][4];
        {
            const float4 bb = *reinterpret_cast<const float4*>(b1 + c0);
            #pragma unroll
            for (int r = 0; r < 8; ++r) {
                acc[r][0] = bb.x; acc[r][1] = bb.y; acc[r][2] = bb.z; acc[r][3] = bb.w;
            }
        }
        for (int k = 0; k < 2 * DIM; k += 4) {
            float w[4][4];
            #pragma unroll
            for (int kk = 0; kk < 4; ++kk)
                *reinterpret_cast<float4*>(w[kk]) =
                    *reinterpret_cast<const float4*>(W1 + (size_t)(k + kk) * HID + c0);
            #pragma unroll
            for (int r = 0; r < 8; ++r) {
                float xr[4];
                *reinterpret_cast<float4*>(xr) =
                    *reinterpret_cast<const float4*>(&Xs[rb + r][k]);
                #pragma unroll
                for (int kk = 0; kk < 4; ++kk)
                    #pragma unroll
                    for (int j = 0; j < 4; ++j)
                        acc[r][j] = fmaf(xr[kk], w[kk][j], acc[r][j]);
            }
        }
        #pragma unroll
        for (int r = 0; r < 8; ++r) {
            float4 h;
            h.x = fmaxf(acc[r][0], 0.f); h.y = fmaxf(acc[r][1], 0.f);
            h.z = fmaxf(acc[r][2], 0.f); h.w = fmaxf(acc[r][3], 0.f);
            *reinterpret_cast<float4*>(&Hs[rb + r][c0]) = h;
        }
    }
    __syncthreads();

    // ---- stage C: out = H @ W2 + b2, W2 is [512][128] row-major
    {
        const int cg = tid & 31;
        const int c0 = cg << 2;              // 4 consecutive out columns
        const int rb = (tid >> 5) << 1;      // row base: 0,2,...,14
        float acc[2][4];
        {
            const float4 bb = *reinterpret_cast<const float4*>(b2 + c0);
            #pragma unroll
            for (int r = 0; r < 2; ++r) {
                acc[r][0] = bb.x; acc[r][1] = bb.y; acc[r][2] = bb.z; acc[r][3] = bb.w;
            }
        }
        for (int k = 0; k < HID; k += 4) {
            float w[4][4];
            #pragma unroll
            for (int kk = 0; kk < 4; ++kk)
                *reinterpret_cast<float4*>(w[kk]) =
                    *reinterpret_cast<const float4*>(W2 + (size_t)(k + kk) * DIM + c0);
            #pragma unroll
            for (int r = 0; r < 2; ++r) {
                float h[4];
                *reinterpret_cast<float4*>(h) =
                    *reinterpret_cast<const float4*>(&Hs[rb + r][k]);
                #pragma unroll
                for (int kk = 0; kk < 4; ++kk)
                    #pragma unroll
                    for (int j = 0; j < 4; ++j)
                        acc[r][j] = fmaf(h[kk], w[kk][j], acc[r][j]);
            }
        }
        #pragma unroll
        for (int r = 0; r < 2; ++r) {
            *reinterpret_cast<float4*>(out + (size_t)(row0 + rb + r) * DIM + c0) =
                make_float4(acc[r][0], acc[r][1], acc[r][2], acc[r][3]);
        }
    }
}

// ---------------------------------------------------------------------------
extern "C" void kernel_launch(void* const* d_in, const int* in_sizes, int n_in,
                              void* d_out, int out_size, void* d_ws, size_t ws_size,
                              hipStream_t stream) {
    const float* x     = (const float*)d_in[0];   // [N,128]
    const float* xvc   = (const float*)d_in[1];   // [B,128]
    const int*   batch = (const int*)d_in[2];     // [N] sorted
    const float* W1    = (const float*)d_in[3];   // [256,512]
    const float* b1    = (const float*)d_in[4];   // [512]
    const float* W2    = (const float*)d_in[5];   // [512,128]
    const float* b2    = (const float*)d_in[6];   // [128]
    float*       out   = (float*)d_out;           // [B,128]

    const int N = in_sizes[2];            // 1,000,000
    const int B = in_sizes[1] / DIM;      // 8192

    // workspace layout: xmean [B*128] f32, then seg_start [B+1] int
    float* xmean    = (float*)d_ws;
    int*   segstart = (int*)((char*)d_ws + (size_t)B * DIM * sizeof(float));

    boundaries_kernel<<<(N + 255) / 256, 256, 0, stream>>>(batch, segstart, N, B);
    seg_mean_kernel<<<B, 256, 0, stream>>>(x, segstart, xmean);
    mlp_kernel<<<B / MLP_ROWS, 256, 0, stream>>>(xmean, xvc, W1, b1, W2, b2, out);
}

// Round 3
// 731.334 us; speedup vs baseline: 1.0121x; 1.0121x over previous
//
#include <hip/hip_runtime.h>

// N=1e6 rows, D=128, B=8192 segments, H=512.
// One fused kernel: block = 256 threads, owns 16 consecutive segments.
//   1) 17 binary searches on sorted batch -> segment boundaries (no dep kernel)
//   2) per-segment mean (contiguous ~1MB row span, float4 coalesced, 4-deep MLP)
//      written straight into LDS X tile (no global xmean round-trip)
//   3) fused MLP: relu([mean,xvc] @ W1 + b1) @ W2 + b2
// No workspace, no atomics, single dispatch.

#define DIM 128
#define HID 512
#define SEGS 16   // segments (= MLP rows) per block

__device__ __forceinline__ void f4add(float4& a, const float4 b) {
    a.x += b.x; a.y += b.y; a.z += b.z; a.w += b.w;
}

__global__ __launch_bounds__(256) void fused_virtual_aggr(
    const float* __restrict__ x, const float* __restrict__ xvc,
    const int* __restrict__ batch,
    const float* __restrict__ W1, const float* __restrict__ b1,
    const float* __restrict__ W2, const float* __restrict__ b2,
    float* __restrict__ out, int N)
{
    __shared__ float Xs[SEGS][2 * DIM];   // 16 KiB: [mean | xvc]
    __shared__ float Hs[SEGS][HID];       // 32 KiB
    __shared__ float4 part[8][32];        // 4 KiB reduce scratch
    __shared__ int bound[SEGS + 1];

    const int tid = threadIdx.x;
    const int s0  = blockIdx.x * SEGS;

    // ---- 1) boundaries: bound[t] = lower_bound(batch, s0+t)
    if (tid <= SEGS) {
        const int s = s0 + tid;
        int lo = 0, hi = N;
        while (lo < hi) {
            const int mid = (lo + hi) >> 1;
            if (batch[mid] < s) lo = mid + 1; else hi = mid;
        }
        bound[tid] = lo;
    }

    // ---- 2a) xvc half of X tile: 512 float4 slots = 16 rows x 32 groups
    #pragma unroll
    for (int i = 0; i < 2; ++i) {
        const int flat = tid + 256 * i;   // 0..511
        const int r  = flat >> 5;         // 0..15
        const int cg = flat & 31;         // 0..31
        *reinterpret_cast<float4*>(&Xs[r][DIM + cg * 4]) =
            *reinterpret_cast<const float4*>(xvc + (size_t)(s0 + r) * DIM + cg * 4);
    }
    __syncthreads();

    // ---- 2b) per-segment mean -> Xs[j][0..127]
    const int colg  = tid & 31;   // float4 col group
    const int phase = tid >> 5;   // 0..7 row phase
    const float* basecol = x + colg * 4;
    for (int j = 0; j < SEGS; ++j) {
        const int lo = bound[j], hi = bound[j + 1];
        float4 a0 = {0,0,0,0}, a1 = {0,0,0,0}, a2 = {0,0,0,0}, a3 = {0,0,0,0};
        int r = lo + phase;
        for (; r + 24 < hi; r += 32) {   // 4 loads in flight per lane
            const float4 v0 = *reinterpret_cast<const float4*>(basecol + (size_t)r * DIM);
            const float4 v1 = *reinterpret_cast<const float4*>(basecol + (size_t)(r + 8) * DIM);
            const float4 v2 = *reinterpret_cast<const float4*>(basecol + (size_t)(r + 16) * DIM);
            const float4 v3 = *reinterpret_cast<const float4*>(basecol + (size_t)(r + 24) * DIM);
            f4add(a0, v0); f4add(a1, v1); f4add(a2, v2); f4add(a3, v3);
        }
        for (; r < hi; r += 8) {
            const float4 v = *reinterpret_cast<const float4*>(basecol + (size_t)r * DIM);
            f4add(a0, v);
        }
        f4add(a0, a1); f4add(a2, a3); f4add(a0, a2);
        part[phase][colg] = a0;
        __syncthreads();
        if (tid < 32) {
            float4 t = part[0][tid];
            #pragma unroll
            for (int p = 1; p < 8; ++p) f4add(t, part[p][tid]);
            const float inv = (hi > lo) ? 1.0f / (float)(hi - lo) : 0.0f;
            t.x *= inv; t.y *= inv; t.z *= inv; t.w *= inv;
            *reinterpret_cast<float4*>(&Xs[j][tid * 4]) = t;
        }
        __syncthreads();
    }

    // ---- 3a) stage B: H = relu(X @ W1 + b1), W1 [256][512] row-major
    {
        const int cg = tid & 127;
        const int c0 = cg << 2;              // 4 consecutive H columns
        const int rb = (tid >> 7) << 3;      // row base: 0 or 8
        float acc[8][4];
        {
            const float4 bb = *reinterpret_cast<const float4*>(b1 + c0);
            #pragma unroll
            for (int r = 0; r < 8; ++r) {
                acc[r][0] = bb.x; acc[r][1] = bb.y; acc[r][2] = bb.z; acc[r][3] = bb.w;
            }
        }
        for (int k = 0; k < 2 * DIM; k += 4) {
            float w[4][4];
            #pragma unroll
            for (int kk = 0; kk < 4; ++kk)
                *reinterpret_cast<float4*>(w[kk]) =
                    *reinterpret_cast<const float4*>(W1 + (size_t)(k + kk) * HID + c0);
            #pragma unroll
            for (int r = 0; r < 8; ++r) {
                float xr[4];
                *reinterpret_cast<float4*>(xr) =
                    *reinterpret_cast<const float4*>(&Xs[rb + r][k]);
                #pragma unroll
                for (int kk = 0; kk < 4; ++kk)
                    #pragma unroll
                    for (int j = 0; j < 4; ++j)
                        acc[r][j] = fmaf(xr[kk], w[kk][j], acc[r][j]);
            }
        }
        #pragma unroll
        for (int r = 0; r < 8; ++r) {
            float4 h;
            h.x = fmaxf(acc[r][0], 0.f); h.y = fmaxf(acc[r][1], 0.f);
            h.z = fmaxf(acc[r][2], 0.f); h.w = fmaxf(acc[r][3], 0.f);
            *reinterpret_cast<float4*>(&Hs[rb + r][c0]) = h;
        }
    }
    __syncthreads();

    // ---- 3b) stage C: out = H @ W2 + b2, W2 [512][128] row-major
    {
        const int cg = tid & 31;
        const int c0 = cg << 2;              // 4 consecutive out columns
        const int rb = (tid >> 5) << 1;      // rows rb, rb+1
        float acc[2][4];
        {
            const float4 bb = *reinterpret_cast<const float4*>(b2 + c0);
            #pragma unroll
            for (int r = 0; r < 2; ++r) {
                acc[r][0] = bb.x; acc[r][1] = bb.y; acc[r][2] = bb.z; acc[r][3] = bb.w;
            }
        }
        for (int k = 0; k < HID; k += 4) {
            float w[4][4];
            #pragma unroll
            for (int kk = 0; kk < 4; ++kk)
                *reinterpret_cast<float4*>(w[kk]) =
                    *reinterpret_cast<const float4*>(W2 + (size_t)(k + kk) * DIM + c0);
            #pragma unroll
            for (int r = 0; r < 2; ++r) {
                float h[4];
                *reinterpret_cast<float4*>(h) =
                    *reinterpret_cast<const float4*>(&Hs[rb + r][k]);
                #pragma unroll
                for (int kk = 0; kk < 4; ++kk)
                    #pragma unroll
                    for (int j = 0; j < 4; ++j)
                        acc[r][j] = fmaf(h[kk], w[kk][j], acc[r][j]);
            }
        }
        #pragma unroll
        for (int r = 0; r < 2; ++r) {
            *reinterpret_cast<float4*>(out + (size_t)(s0 + rb + r) * DIM + c0) =
                make_float4(acc[r][0], acc[r][1], acc[r][2], acc[r][3]);
        }
    }
}

// ---------------------------------------------------------------------------
extern "C" void kernel_launch(void* const* d_in, const int* in_sizes, int n_in,
                              void* d_out, int out_size, void* d_ws, size_t ws_size,
                              hipStream_t stream) {
    const float* x     = (const float*)d_in[0];   // [N,128]
    const float* xvc   = (const float*)d_in[1];   // [B,128]
    const int*   batch = (const int*)d_in[2];     // [N] sorted
    const float* W1    = (const float*)d_in[3];   // [256,512]
    const float* b1    = (const float*)d_in[4];   // [512]
    const float* W2    = (const float*)d_in[5];   // [512,128]
    const float* b2    = (const float*)d_in[6];   // [128]
    float*       out   = (float*)d_out;           // [B,128]

    const int N = in_sizes[2];            // 1,000,000
    const int B = in_sizes[1] / DIM;      // 8192

    fused_virtual_aggr<<<B / SEGS, 256, 0, stream>>>(
        x, xvc, batch, W1, b1, W2, b2, out, N);
}